// Round 9
// baseline (3404.074 us; speedup 1.0000x reference)
//
#include <hip/hip_runtime.h>
#include <stdint.h>

// LSTM B=64,T=512,I=512,H=512. out hs[T,B,H] fp32.
// Persistent: 4 batch-groups x 32 wgs (128 wgs, 256 thr). Each wg: 16 batch
// rows x 16 h-cols (all 4 gates). Weights (K=1024=[w_ih|w_hh]) in registers
// as bf16 MFMA fragments, transposed-C: acc = mfma(W_frag, A_frag) so each
// lane's 4 acc regs = gates {i,f,g,o} of one (batch,col) -> lane-local cell.
// h exchange (R9): SELF-DESCRIBING tagged u64 data words [h-pair:32|tag:32]
// (relaxed agent atomics; per-word atomicity -> race-free like R2-R7) +
// per-wave FLAGS as a cheap spin gate (2 dword loads/lane/round). Bulk data
// read is tag-VERIFIED (stale flag lies are caught and re-read). One barrier
// per step (hazard-checked). Probe+x loads issued at step start so the flag
// check waits vmcnt(8) and x stays in flight. Out stores batched 8 steps.

#define BATCH 64
#define TSTEPS 512
#define IDIM 512
#define HDIM 512
#define WGS_PER_GROUP 32
#define NGROUPS 4
#define BB 16
#define NWG (WGS_PER_GROUP * NGROUPS)
#define HDAT_U64 (BB * (HDIM / 2))   // 4096 u64 = 32KB per (parity,group)
#define NFLAGS 128                   // 32 wgs x 4 waves per (parity,group)

typedef __attribute__((ext_vector_type(4))) float f32x4;
typedef __attribute__((ext_vector_type(8))) short bf16x8;
typedef __attribute__((ext_vector_type(4))) unsigned int u32x4;

#define AL(p) __hip_atomic_load((p), __ATOMIC_RELAXED, __HIP_MEMORY_SCOPE_AGENT)
#define AS(p, v) __hip_atomic_store((p), (v), __ATOMIC_RELAXED, __HIP_MEMORY_SCOPE_AGENT)

__device__ inline unsigned short f2bf(float f) {
  unsigned u = __builtin_bit_cast(unsigned, f);
  u = (u + 0x7fffu + ((u >> 16) & 1u)) >> 16;  // RNE
  return (unsigned short)u;
}
__device__ inline float fast_sigmoid(float x) { return 1.f / (1.f + __expf(-x)); }
__device__ inline float fast_tanh(float x) { return 1.f - 2.f / (__expf(2.f * x) + 1.f); }

__global__ void lstm_init(const float* __restrict__ b_ih, const float* __restrict__ b_hh,
                          float* __restrict__ bias, uint64_t* __restrict__ hdat,
                          uint32_t* __restrict__ flags) {
  const int i = blockIdx.x * blockDim.x + threadIdx.x;  // 2048 threads
  if (i < 4 * HDIM) bias[i] = b_ih[i] + b_hh[i];
  // zero tagged data + flags: tag 0 never matches t>=1; clears graph-replay
  // leftovers so every replay is deterministic.
  for (int j = i; j < 2 * NGROUPS * HDAT_U64; j += 2048) hdat[j] = 0ull;
  if (i < 2 * NGROUPS * NFLAGS) flags[i] = 0u;
}

__global__ __launch_bounds__(256, 1)
void lstm_persistent(const float* __restrict__ x,
                     const float* __restrict__ w_ih,
                     const float* __restrict__ w_hh,
                     const float* __restrict__ bias,
                     uint64_t* hdat,     // [2][NGROUPS][BB][256] tagged pairs
                     uint32_t* flags,    // [2][NGROUPS][128]
                     float* __restrict__ out) {
  __shared__ unsigned short X_lds[2][16 * IDIM];   // 2 x 16KB, XOR-swizzled
  __shared__ unsigned short H_lds[2][16 * HDIM];   // 2 x 16KB, XOR-swizzled

  const int wg = blockIdx.x;
  const int group = wg >> 5;
  const int wgg = wg & 31;
  const int b0 = group * BB;
  const int h0 = wgg * 16;
  const int tid = threadIdx.x;
  const int wave = tid >> 6;
  const int lane = tid & 63;
  const int hi4 = lane >> 4;

  // ---- one-time: weight A-fragments (transposed-C form) ----
  const int nn = lane & 15;
  const int growf = (nn & 3) * HDIM + h0 + wave * 4 + (nn >> 2);  // gate row
  bf16x8 breg[32];
#pragma unroll
  for (int kt = 0; kt < 32; ++kt) {
    const int k = kt * 32 + hi4 * 8;
    const float* src = (k < IDIM) ? (w_ih + (size_t)growf * IDIM + k)
                                  : (w_hh + (size_t)growf * HDIM + (k - IDIM));
    bf16x8 v;
#pragma unroll
    for (int j = 0; j < 8; ++j) v[j] = (short)f2bf(src[j]);
    breg[kt] = v;
  }
  const int mycol = h0 + wave * 4 + hi4;   // this lane's h column
  const float bv0 = bias[0 * HDIM + mycol];
  const float bv1 = bias[1 * HDIM + mycol];
  const float bv2 = bias[2 * HDIM + mycol];
  const float bv3 = bias[3 * HDIM + mycol];

  const int mrow = lane & 15;             // MFMA B-operand row = batch
  const int rswz = (mrow & 7) << 4;
  const int bi = lane & 15;

  // ---- prologue: stage x_0 -> X_lds[0] (conflict-free rows wave+q*4) ----
#pragma unroll
  for (int q = 0; q < 4; ++q) {
    const int r = wave + q * 4;
    const float* xp = x + ((size_t)(b0 + r) * TSTEPS + 0) * IDIM + lane * 8;
    float4 fa = *(const float4*)xp;
    float4 fb = *(const float4*)(xp + 4);
    bf16x8 v;
    v[0] = (short)f2bf(fa.x); v[1] = (short)f2bf(fa.y);
    v[2] = (short)f2bf(fa.z); v[3] = (short)f2bf(fa.w);
    v[4] = (short)f2bf(fb.x); v[5] = (short)f2bf(fb.y);
    v[6] = (short)f2bf(fb.z); v[7] = (short)f2bf(fb.w);
    *(bf16x8*)((char*)&X_lds[0][0] + ((r * 1024 + lane * 16) ^ ((r & 7) << 4))) = v;
  }
  __syncthreads();

  float c = 0.f;   // cell state for (batch=lane&15, col=mycol)
  float hout[8];
  const size_t obase = (size_t)(b0 + bi) * HDIM + mycol;

  for (int tb = 0; tb < TSTEPS; tb += 8) {
#pragma unroll
    for (int u = 0; u < 8; ++u) {
      const int t = tb + u;
      const int cur = t & 1;
      const uint32_t tu = (uint32_t)t;

      // ---- issue flag probe (oldest vmem -> check waits vmcnt(8)) ----
      const uint32_t* fp = flags + ((size_t)cur * NGROUPS + group) * NFLAGS + lane * 2;
      uint32_t f0 = tu, f1 = tu;
      if (t > 0) { f0 = AL(fp); f1 = AL(fp + 1); }

      // ---- issue x_{t+1} loads (in flight through phase A + spin) ----
      float4 xf[8];
      if (t + 1 < TSTEPS) {
#pragma unroll
        for (int q = 0; q < 4; ++q) {
          const float* xp = x + ((size_t)(b0 + wave + q * 4) * TSTEPS + (t + 1)) * IDIM + lane * 8;
          xf[q * 2] = *(const float4*)xp;
          xf[q * 2 + 1] = *(const float4*)(xp + 4);
        }
      }

      // ---- phase A: x-part MFMAs (kt 0..15) ----
      f32x4 acc0 = {0.f, 0.f, 0.f, 0.f}, acc1 = {0.f, 0.f, 0.f, 0.f};
#pragma unroll
      for (int kt = 0; kt < 16; kt += 2) {
        bf16x8 a0 = *(const bf16x8*)((const char*)&X_lds[cur][0] +
                      ((mrow * 1024 + (kt * 4 + hi4) * 16) ^ rswz));
        acc0 = __builtin_amdgcn_mfma_f32_16x16x32_bf16(breg[kt], a0, acc0, 0, 0, 0);
        bf16x8 a1 = *(const bf16x8*)((const char*)&X_lds[cur][0] +
                      ((mrow * 1024 + ((kt + 1) * 4 + hi4) * 16) ^ rswz));
        acc1 = __builtin_amdgcn_mfma_f32_16x16x32_bf16(breg[kt + 1], a1, acc1, 0, 0, 0);
      }

      // ---- flag spin (2 dwords/lane/round) + tagged bulk read + verify ----
      if (t > 0) {
        while (!__all((int)((f0 == tu) & (f1 == tu)))) { f0 = AL(fp); f1 = AL(fp + 1); }
        const uint64_t* dp = hdat + ((size_t)cur * NGROUPS + group) * HDAT_U64
                           + (size_t)wave * 1024 + lane * 4;
        uint64_t hu[16];
        while (true) {
#pragma unroll
          for (int j = 0; j < 4; ++j)
#pragma unroll
            for (int e = 0; e < 4; ++e)
              hu[j * 4 + e] = AL(dp + j * 256 + e);
          bool ok = true;
#pragma unroll
          for (int k2 = 0; k2 < 16; ++k2) ok &= ((uint32_t)hu[k2] == tu);
          if (__all((int)ok)) break;   // tags are the real guard (flags may lie)
        }
        // restage h -> H_lds[cur]: word g = wave*1024+j*256+lane*4+e ->
        // row = wave*4+j, u32-pair col = lane*4+e (byte lane*16+4e), swizzled.
#pragma unroll
        for (int j = 0; j < 4; ++j) {
          u32x4 w = { (uint32_t)(hu[j * 4 + 0] >> 32), (uint32_t)(hu[j * 4 + 1] >> 32),
                      (uint32_t)(hu[j * 4 + 2] >> 32), (uint32_t)(hu[j * 4 + 3] >> 32) };
          const int r = wave * 4 + j;
          *(u32x4*)((char*)&H_lds[cur][0] + ((r * 1024 + lane * 16) ^ ((r & 7) << 4))) = w;
        }
      }

      // ---- stage x_{t+1} -> X_lds[cur^1] (compiler waits xf here) ----
      if (t + 1 < TSTEPS) {
#pragma unroll
        for (int q = 0; q < 4; ++q) {
          float4 fa = xf[q * 2], fb = xf[q * 2 + 1];
          bf16x8 v;
          v[0] = (short)f2bf(fa.x); v[1] = (short)f2bf(fa.y);
          v[2] = (short)f2bf(fa.z); v[3] = (short)f2bf(fa.w);
          v[4] = (short)f2bf(fb.x); v[5] = (short)f2bf(fb.y);
          v[6] = (short)f2bf(fb.z); v[7] = (short)f2bf(fb.w);
          const int r = wave + q * 4;
          *(bf16x8*)((char*)&X_lds[cur ^ 1][0] + ((r * 1024 + lane * 16) ^ ((r & 7) << 4))) = v;
        }
      }
      __syncthreads();   // the ONLY barrier per step

      // ---- phase C: h-part MFMAs (kt 16..31) ----
      if (t > 0) {
#pragma unroll
        for (int kt = 0; kt < 16; kt += 2) {
          bf16x8 a0 = *(const bf16x8*)((const char*)&H_lds[cur][0] +
                        ((mrow * 1024 + (kt * 4 + hi4) * 16) ^ rswz));
          acc0 = __builtin_amdgcn_mfma_f32_16x16x32_bf16(breg[16 + kt], a0, acc0, 0, 0, 0);
          bf16x8 a1 = *(const bf16x8*)((const char*)&H_lds[cur][0] +
                        ((mrow * 1024 + ((kt + 1) * 4 + hi4) * 16) ^ rswz));
          acc1 = __builtin_amdgcn_mfma_f32_16x16x32_bf16(breg[17 + kt], a1, acc1, 0, 0, 0);
        }
      }

      // ---- elementwise: lane-local gates i,f,g,o in acc regs 0..3 ----
      const float gi = acc0[0] + acc1[0] + bv0;
      const float gf = acc0[1] + acc1[1] + bv1;
      const float gg = acc0[2] + acc1[2] + bv2;
      const float go = acc0[3] + acc1[3] + bv3;
      c = fast_sigmoid(gf) * c + fast_sigmoid(gi) * fast_tanh(gg);
      const float hval = fast_sigmoid(go) * fast_tanh(c);

      // ---- publish tagged h_{t+1}; drain; per-wave flag ----
      if (t + 1 < TSTEPS) {
        const unsigned hb = (unsigned)f2bf(hval);
        const unsigned pb = (unsigned)__shfl_xor((int)hb, 16, 64);
        if ((hi4 & 1) == 0) {
          const uint64_t val = (uint64_t)(uint32_t)(t + 1)
                             | ((uint64_t)(hb | (pb << 16)) << 32);
          AS(hdat + ((size_t)((t + 1) & 1) * NGROUPS + group) * HDAT_U64
               + (size_t)bi * 256 + (mycol >> 1), val);
        }
        asm volatile("s_waitcnt vmcnt(0)" ::: "memory");
        __builtin_amdgcn_sched_barrier(0);
        if (lane == 0) {
          AS(flags + ((size_t)((t + 1) & 1) * NGROUPS + group) * NFLAGS + wgg * 4 + wave,
             (uint32_t)(t + 1));
        }
      }
      hout[u] = hval;   // static index (unrolled) -> stays in VGPRs
    }
    // ---- batched out flush (off the per-step critical path) ----
#pragma unroll
    for (int k = 0; k < 8; ++k)
      out[(size_t)(tb + k) * (BATCH * HDIM) + obase] = hout[k];
  }
}

extern "C" void kernel_launch(void* const* d_in, const int* in_sizes, int n_in,
                              void* d_out, int out_size, void* d_ws, size_t ws_size,
                              hipStream_t stream) {
  const float* x    = (const float*)d_in[0];
  const float* w_ih = (const float*)d_in[1];
  const float* w_hh = (const float*)d_in[2];
  const float* b_ih = (const float*)d_in[3];
  const float* b_hh = (const float*)d_in[4];
  float* out = (float*)d_out;

  char* ws = (char*)d_ws;
  float* bias = (float*)ws;                              // 8KB
  uint64_t* hdat = (uint64_t*)(ws + 8192);               // 256KB tagged pairs
  uint32_t* flags = (uint32_t*)(ws + 8192 + 262144);     // 4KB

  lstm_init<<<8, 256, 0, stream>>>(b_ih, b_hh, bias, hdat, flags);
  lstm_persistent<<<NWG, 256, 0, stream>>>(x, w_ih, w_hh, bias, hdat, flags, out);
}

// Round 11
// 1154.311 us; speedup vs baseline: 2.9490x; 2.9490x over previous
//
#include <hip/hip_runtime.h>
#include <stdint.h>

// LSTM B=64,T=512,I=512,H=512. out hs[T,B,H] fp32.
// R11 = R7 proven skeleton + halved groups + conflict-free staging.
// 8 groups x 8 batch rows; each group = 32 wgs x 16 h-cols (256 wgs, 256thr).
// Weights (K=1024=[w_ih|w_hh]) in regs as bf16 MFMA fragments, transposed-C:
// acc = mfma(W_frag, A_frag) -> lane's 4 acc regs = gates {i,f,g,o} of one
// (batch,col) -> lane-local cell update.
// h exchange: self-describing tagged u64 [data:32|tag:32], relaxed-agent
// semantics (sc0 sc1 loads = L1/L2 bypass, proven R7/R8/R9). Poll = 4x
// dwordx4 per lane (16KB/wg working set), tag-verified, re-read until all
// tags match (no flags). ONE barrier/step (hazard-audited). x_{t+2} reg
// prefetch issued post-barrier. out stores batched 8 steps in registers.

#define BATCH 64
#define TSTEPS 512
#define IDIM 512
#define HDIM 512
#define NGROUPS 8
#define BB 8                          // batch rows per group
#define NWG (NGROUPS * 32)            // 256 wgs
#define HDAT_U64 (BB * (HDIM / 2))    // 2048 u64 = 16KB per (parity,group)

typedef __attribute__((ext_vector_type(4))) float f32x4;
typedef __attribute__((ext_vector_type(8))) short bf16x8;
typedef __attribute__((ext_vector_type(4))) unsigned int u32x4;
typedef __attribute__((ext_vector_type(2))) unsigned int u32x2;

#define AS(p, v) __hip_atomic_store((p), (v), __ATOMIC_RELAXED, __HIP_MEMORY_SCOPE_AGENT)

__device__ inline unsigned short f2bf(float f) {
  unsigned u = __builtin_bit_cast(unsigned, f);
  u = (u + 0x7fffu + ((u >> 16) & 1u)) >> 16;  // RNE
  return (unsigned short)u;
}
__device__ inline float fast_sigmoid(float x) { return 1.f / (1.f + __expf(-x)); }
__device__ inline float fast_tanh(float x) { return 1.f - 2.f / (__expf(2.f * x) + 1.f); }

__global__ void lstm_init(const float* __restrict__ b_ih, const float* __restrict__ b_hh,
                          float* __restrict__ bias, uint64_t* __restrict__ hdat) {
  const int i = blockIdx.x * blockDim.x + threadIdx.x;  // 2048 threads
  if (i < 4 * HDIM) bias[i] = b_ih[i] + b_hh[i];
  // zero tagged words (tag 0 never matches t>=1); clears graph-replay state
  for (int j = i; j < 2 * NGROUPS * HDAT_U64; j += 2048) hdat[j] = 0ull;
}

__global__ __launch_bounds__(256, 1)
void lstm_persistent(const float* __restrict__ x,
                     const float* __restrict__ w_ih,
                     const float* __restrict__ w_hh,
                     const float* __restrict__ bias,
                     uint64_t* hdat,     // [2][NGROUPS][BB][256] tagged pairs
                     float* __restrict__ out) {
  __shared__ unsigned short X_lds[2][8 * IDIM];   // 2 x 8KB, XOR-swizzled
  __shared__ unsigned short H_lds[2][8 * HDIM];   // 2 x 8KB, XOR-swizzled

  const int wg = blockIdx.x;
  const int group = wg >> 5;           // 0..7
  const int rank = wg & 31;
  const int b0 = group * BB;
  const int h0 = rank * 16;
  const int tid = threadIdx.x;
  const int wave = tid >> 6;
  const int lane = tid & 63;
  const int hi4 = lane >> 4;
  const int nn = lane & 15;

  // ---- one-time: weight A-fragments (transposed-C form) ----
  const int growf = (nn & 3) * HDIM + h0 + wave * 4 + (nn >> 2);  // gate row
  bf16x8 breg[32];
#pragma unroll
  for (int kt = 0; kt < 32; ++kt) {
    const int k = kt * 32 + hi4 * 8;
    const float* src = (k < IDIM) ? (w_ih + (size_t)growf * IDIM + k)
                                  : (w_hh + (size_t)growf * HDIM + (k - IDIM));
    bf16x8 v;
#pragma unroll
    for (int j = 0; j < 8; ++j) v[j] = (short)f2bf(src[j]);
    breg[kt] = v;
  }
  const int mycol = h0 + wave * 4 + hi4;
  const float bv0 = bias[0 * HDIM + mycol];
  const float bv1 = bias[1 * HDIM + mycol];
  const float bv2 = bias[2 * HDIM + mycol];
  const float bv3 = bias[3 * HDIM + mycol];

  const int bi = lane & 15;          // C col = batch (bi>=8 lanes are dupes)
  const int mr8 = bi & 7;            // MFMA B-row / LDS row (8 real rows)
  const int rswz = mr8 << 4;

  // ---- prologue: stage x_0 rows 0..7 -> X_lds[0]; preload xfA = x_1 ----
#pragma unroll
  for (int q = 0; q < 2; ++q) {
    const int r = wave + q * 4;
    const float* xp = x + ((size_t)(b0 + r) * TSTEPS + 0) * IDIM + lane * 8;
    float4 fa = *(const float4*)xp;
    float4 fb = *(const float4*)(xp + 4);
    bf16x8 v;
    v[0] = (short)f2bf(fa.x); v[1] = (short)f2bf(fa.y);
    v[2] = (short)f2bf(fa.z); v[3] = (short)f2bf(fa.w);
    v[4] = (short)f2bf(fb.x); v[5] = (short)f2bf(fb.y);
    v[6] = (short)f2bf(fb.z); v[7] = (short)f2bf(fb.w);
    *(bf16x8*)((char*)&X_lds[0][0] + ((r * 1024 + lane * 16) ^ ((r & 7) << 4))) = v;
  }
  float4 xfA[4], xfB[4];
#pragma unroll
  for (int q = 0; q < 2; ++q) {
    const float* xp = x + ((size_t)(b0 + wave + q * 4) * TSTEPS + 1) * IDIM + lane * 8;
    xfA[q * 2] = *(const float4*)xp;
    xfA[q * 2 + 1] = *(const float4*)(xp + 4);
  }
  __syncthreads();

  float c = 0.f;   // cell state for (batch=bi, col=mycol); bi>=8 lanes dup
  float hout[8];
  const size_t obase = (size_t)(b0 + bi) * HDIM + mycol;   // valid for bi<8

  for (int tb = 0; tb < TSTEPS; tb += 8) {
#pragma unroll
    for (int u = 0; u < 8; ++u) {
      const int t = tb + u;
      const int cur = t & 1;
      const uint32_t tu = (uint32_t)t;

      // ---- phase A: x-part MFMAs (kt 0..15) ----
      f32x4 acc0 = {0.f, 0.f, 0.f, 0.f}, acc1 = {0.f, 0.f, 0.f, 0.f};
#pragma unroll
      for (int kt = 0; kt < 16; kt += 2) {
        bf16x8 a0 = *(const bf16x8*)((const char*)&X_lds[cur][0] +
                      ((mr8 * 1024 + (kt * 4 + hi4) * 16) ^ rswz));
        acc0 = __builtin_amdgcn_mfma_f32_16x16x32_bf16(breg[kt], a0, acc0, 0, 0, 0);
        bf16x8 a1 = *(const bf16x8*)((const char*)&X_lds[cur][0] +
                      ((mr8 * 1024 + ((kt + 1) * 4 + hi4) * 16) ^ rswz));
        acc1 = __builtin_amdgcn_mfma_f32_16x16x32_bf16(breg[kt + 1], a1, acc1, 0, 0, 0);
      }

      // ---- tagged poll: lane reads 8 u64 via 4x dwordx4 sc0 sc1;
      //      every u64 = [data|tag]; re-read until ALL tags == t ----
      if (t > 0) {
        const uint64_t* dp = hdat + ((size_t)cur * NGROUPS + group) * HDAT_U64
                           + (size_t)wave * 512 + lane * 2;
        u32x4 d0, d1, d2, d3;   // [tag,data,tag,data] per vec
        while (true) {
          asm volatile(
            "global_load_dwordx4 %0, %4, off sc0 sc1\n\t"
            "global_load_dwordx4 %1, %4, off offset:1024 sc0 sc1\n\t"
            "global_load_dwordx4 %2, %4, off offset:2048 sc0 sc1\n\t"
            "global_load_dwordx4 %3, %4, off offset:3072 sc0 sc1\n\t"
            "s_waitcnt vmcnt(0)"
            : "=&v"(d0), "=&v"(d1), "=&v"(d2), "=&v"(d3)
            : "v"(dp) : "memory");
          __builtin_amdgcn_sched_barrier(0);
          bool ok = (d0[0] == tu) & (d0[2] == tu) & (d1[0] == tu) & (d1[2] == tu)
                  & (d2[0] == tu) & (d2[2] == tu) & (d3[0] == tu) & (d3[2] == tu);
          if (__all((int)ok)) break;
        }
        // restage h -> H_lds[cur]: word g = wave*512 + j*128 + lane*2 + {0,1}
        // -> row = g>>8 = wave*2+(j>>1), pair = g&255 -> byte
        // row*1024 + (j&1)*512 + lane*8, swizzled; b64 write (2-way = free).
#pragma unroll
        for (int j = 0; j < 4; ++j) {
          const int row = wave * 2 + (j >> 1);
          const int byte = (row * 1024 + (j & 1) * 512 + lane * 8) ^ ((row & 7) << 4);
          u32x2 w;
          if (j == 0)      { w[0] = d0[1]; w[1] = d0[3]; }
          else if (j == 1) { w[0] = d1[1]; w[1] = d1[3]; }
          else if (j == 2) { w[0] = d2[1]; w[1] = d2[3]; }
          else             { w[0] = d3[1]; w[1] = d3[3]; }
          *(u32x2*)((char*)&H_lds[cur][0] + byte) = w;
        }
      }

      // ---- stage x_{t+1} -> X_lds[cur^1] from the reg bank ----
      if (t + 1 < TSTEPS) {
#pragma unroll
        for (int q = 0; q < 2; ++q) {
          float4 fa, fb;
          if ((u & 1) == 0) { fa = xfA[q * 2]; fb = xfA[q * 2 + 1]; }
          else              { fa = xfB[q * 2]; fb = xfB[q * 2 + 1]; }
          bf16x8 v;
          v[0] = (short)f2bf(fa.x); v[1] = (short)f2bf(fa.y);
          v[2] = (short)f2bf(fa.z); v[3] = (short)f2bf(fa.w);
          v[4] = (short)f2bf(fb.x); v[5] = (short)f2bf(fb.y);
          v[6] = (short)f2bf(fb.z); v[7] = (short)f2bf(fb.w);
          const int r = wave + q * 4;
          *(bf16x8*)((char*)&X_lds[cur ^ 1][0] + ((r * 1024 + lane * 16) ^ ((r & 7) << 4))) = v;
        }
      }
      __syncthreads();   // the ONLY barrier per step (no fresh vmem before it)

      // ---- x_{t+2} refill issue (post-barrier: never drained by it) ----
      if (t + 2 < TSTEPS) {
#pragma unroll
        for (int q = 0; q < 2; ++q) {
          const float* xp = x + ((size_t)(b0 + wave + q * 4) * TSTEPS + (t + 2)) * IDIM + lane * 8;
          if ((u & 1) == 0) { xfB[q * 2] = *(const float4*)xp; xfB[q * 2 + 1] = *(const float4*)(xp + 4); }
          else              { xfA[q * 2] = *(const float4*)xp; xfA[q * 2 + 1] = *(const float4*)(xp + 4); }
        }
      }
      __builtin_amdgcn_sched_barrier(0);

      // ---- phase C: h-part MFMAs (kt 16..31) ----
      if (t > 0) {
#pragma unroll
        for (int kt = 0; kt < 16; kt += 2) {
          bf16x8 a0 = *(const bf16x8*)((const char*)&H_lds[cur][0] +
                        ((mr8 * 1024 + (kt * 4 + hi4) * 16) ^ rswz));
          acc0 = __builtin_amdgcn_mfma_f32_16x16x32_bf16(breg[16 + kt], a0, acc0, 0, 0, 0);
          bf16x8 a1 = *(const bf16x8*)((const char*)&H_lds[cur][0] +
                        ((mr8 * 1024 + ((kt + 1) * 4 + hi4) * 16) ^ rswz));
          acc1 = __builtin_amdgcn_mfma_f32_16x16x32_bf16(breg[17 + kt], a1, acc1, 0, 0, 0);
        }
      }

      // ---- elementwise: lane-local gates i,f,g,o in acc regs 0..3 ----
      const float gi = acc0[0] + acc1[0] + bv0;
      const float gf = acc0[1] + acc1[1] + bv1;
      const float gg = acc0[2] + acc1[2] + bv2;
      const float go = acc0[3] + acc1[3] + bv3;
      c = fast_sigmoid(gf) * c + fast_sigmoid(gi) * fast_tanh(gg);
      const float hval = fast_sigmoid(go) * fast_tanh(c);

      // ---- publish tagged h_{t+1}: single u64 store (untearable) ----
      if (t + 1 < TSTEPS) {
        const unsigned hb = (unsigned)f2bf(hval);
        const unsigned pb = (unsigned)__shfl_xor((int)hb, 16, 64);
        if (bi < 8 && (hi4 & 1) == 0) {
          const uint64_t val = (uint64_t)(uint32_t)(t + 1)
                             | ((uint64_t)(hb | (pb << 16)) << 32);
          AS(hdat + ((size_t)((t + 1) & 1) * NGROUPS + group) * HDAT_U64
               + (size_t)bi * 256 + (mycol >> 1), val);
        }
      }
      hout[u] = hval;   // static index (unrolled) -> stays in VGPRs
    }
    // ---- batched out flush (couples into a poll only once per 8 steps) ----
    if (bi < 8) {
#pragma unroll
      for (int k = 0; k < 8; ++k)
        out[(size_t)(tb + k) * (BATCH * HDIM) + obase] = hout[k];
    }
  }
}

extern "C" void kernel_launch(void* const* d_in, const int* in_sizes, int n_in,
                              void* d_out, int out_size, void* d_ws, size_t ws_size,
                              hipStream_t stream) {
  const float* x    = (const float*)d_in[0];
  const float* w_ih = (const float*)d_in[1];
  const float* w_hh = (const float*)d_in[2];
  const float* b_ih = (const float*)d_in[3];
  const float* b_hh = (const float*)d_in[4];
  float* out = (float*)d_out;

  char* ws = (char*)d_ws;
  float* bias = (float*)ws;                              // 8KB
  uint64_t* hdat = (uint64_t*)(ws + 8192);               // 256KB tagged pairs

  lstm_init<<<8, 256, 0, stream>>>(b_ih, b_hh, bias, hdat);
  lstm_persistent<<<NWG, 256, 0, stream>>>(x, w_ih, w_hh, bias, hdat, out);
}